// Round 4
// baseline (850.660 us; speedup 1.0000x reference)
//
#include <hip/hip_runtime.h>
#include <cmath>

#define MP1 524288
#define NXP 32768

typedef float vfloat4 __attribute__((ext_vector_type(4)));

// ws layout (float offsets):
//   [0,128)              b_acc (zeroed by prep1; ws is poisoned each launch)
//   [128,256)            cvec = Wt3^T (b_acc+bb)
//   [256]                u_const = dot(b, bt3)
//   [300,428)            DIAGNOSTIC dummy atomic target for gemv replicas
//   [512, 512+16384)     WT2t[k*128+j] = Wt2[j*128+k]
//   [16896, 16896+4096)  WE2t[i*64+m]  = We2[m*64+i]

__global__ __launch_bounds__(256) void prep1_k(const float* __restrict__ Wt2,
                                               const float* __restrict__ We2,
                                               float* __restrict__ ws) {
    int idx = blockIdx.x * 256 + threadIdx.x;
    if (idx < 128) ws[idx] = 0.0f;
    if (idx < 16384) {
        int j = idx >> 7, k = idx & 127;
        ws[512 + k * 128 + j] = Wt2[idx];
    }
    if (idx < 4096) {
        int m = idx >> 6, i = idx & 63;
        ws[16896 + i * 64 + m] = We2[idx];
    }
}

// DIAGNOSTIC: replicated x4 via blockIdx.z. Replica 0 is the real gemv;
// replicas 1-3 re-stream Wb identically but atomically add into dead ws
// region [300,428) so the visible result is bit-identical. Purpose: push
// gemv_k above the 160us poison fills so its counters surface in top-5.
__global__ __launch_bounds__(256) void gemv_k(const float* __restrict__ Wb,
                                              const float* __restrict__ a,
                                              float* __restrict__ b_acc) {
    const int row = blockIdx.x;
    const int chunk = blockIdx.y;
    const int rep = blockIdx.z;
    const int t = threadIdx.x;
    size_t base = (size_t)row * MP1 + (size_t)chunk * 16384;
    const vfloat4* W4 = (const vfloat4*)(Wb + base);
    const float4* A4 = (const float4*)(a + (size_t)chunk * 16384);
    float sum = 0.0f;
#pragma unroll
    for (int it = 0; it < 16; ++it) {
        vfloat4 w = __builtin_nontemporal_load(&W4[t + it * 256]);
        float4 av = A4[t + it * 256];
        sum += w[0] * av.x + w[1] * av.y + w[2] * av.z + w[3] * av.w;
    }
#pragma unroll
    for (int off = 32; off > 0; off >>= 1) sum += __shfl_down(sum, off, 64);
    __shared__ float red[4];
    int wid = t >> 6;
    if ((t & 63) == 0) red[wid] = sum;
    __syncthreads();
    if (t == 0) {
        float* dst = b_acc + (rep == 0 ? 0 : 300);
        atomicAdd(&dst[row], red[0] + red[1] + red[2] + red[3]);
    }
}

__global__ __launch_bounds__(128) void prep2_k(const float* __restrict__ ws_in,
                                               const float* __restrict__ bb,
                                               const float* __restrict__ Wt3,
                                               const float* __restrict__ bt3,
                                               float* __restrict__ ws) {
    int k = threadIdx.x;
    float cv = 0.0f;
    for (int j = 0; j < 128; ++j)
        cv = fmaf(ws_in[j] + bb[j], Wt3[j * 128 + k], cv);
    ws[128 + k] = cv;
    float p = (ws_in[k] + bb[k]) * bt3[k];
#pragma unroll
    for (int off = 32; off > 0; off >>= 1) p += __shfl_down(p, off, 64);
    __shared__ float red[2];
    if ((k & 63) == 0) red[k >> 6] = p;
    __syncthreads();
    if (k == 0) ws[256] = red[0] + red[1];
}

// point_k: all-LDS hot loops. THIS ROUND: (1) forced #pragma unroll 1 on both
// hot loops — the previous unroll 2 doubled interleaved live ranges past the
// 128-VGPR launch_bounds cap (64 acc regs in B, 72 in C, + staged weights),
// the prime suspect for scratch spills; (2) DIAGNOSTIC x4 replication via
// blockIdx.x & 511 (identical values written to out — benign) to surface
// point_k's own counters (VALUBusy, FETCH/WRITE = spill evidence) in top-5.
// LDS (floats):
#define SW_WT1 0        // 256: Wt1 (interleaved [k][2], matches source layout)
#define SW_BT1 256      // 128
#define SW_BT2 384      // 128
#define SW_CVEC 512     // 128
#define SW_WE1 640      // 128
#define SW_BE1 768      // 64
#define SW_BE2 832      // 64
#define SW_WE3 896      // 64
#define UREDP 960       // 256: reduced u jets, plane-major [r*64+p]
#define H1V_ 1216       // 8192: trunk h1 [k*64+p]; phase C reuses [0,4096) for
                        //       energy h, [4096,7168) for FRED planes
#define FREDP (H1V_ + 4096)
#define SCR_ 9408       // 4096: Wt2t 32-k chunk (B) -> RED planes -> We2t (C)
#define LDSF 13504      // 54,016 B -> 2 blocks/CU

__global__ __launch_bounds__(512, 4) void point_k(const float* __restrict__ x,
                                                  const float* __restrict__ tptr,
                                                  const float* __restrict__ Wt1,
                                                  const float* __restrict__ bt1,
                                                  const float* __restrict__ bt2,
                                                  const float* __restrict__ We1,
                                                  const float* __restrict__ be1,
                                                  const float* __restrict__ be2,
                                                  const float* __restrict__ We3,
                                                  const float* __restrict__ ws,
                                                  float* __restrict__ out) {
    __shared__ __align__(16) float lds[LDSF];
    const int tid = threadIdx.x;
    const int p = tid & 63;
    const int slice = __builtin_amdgcn_readfirstlane(tid >> 6);
    const int bx = blockIdx.x & 511;   // DIAGNOSTIC: 4 identical replicas
    const int i = bx * 64 + p;
    const float xi = x[i];
    const float tt = tptr[0];
    const float u_const = ws[256];

    // ---- stage all small weight tables into LDS (960 floats) ----
    if (tid < 256) lds[SW_WT1 + tid] = Wt1[tid];
    else if (tid < 384) lds[SW_BT1 + tid - 256] = bt1[tid - 256];
    else lds[SW_BT2 + tid - 384] = bt2[tid - 384];
    {
        int o = 512 + tid;
        if (o < 640) lds[o] = ws[128 + (o - 512)];        // cvec
        else if (o < 768) lds[o] = We1[o - 640];
        else if (o < 832) lds[o] = be1[o - 768];
        else if (o < 896) lds[o] = be2[o - 832];
        else if (o < 960) lds[o] = We3[o - 896];
    }
    __syncthreads();

    // ---- Phase A: trunk layer-1 tanh values (16 k's per thread) ----
#pragma unroll
    for (int q = 0; q < 16; ++q) {
        int k = slice * 16 + q;
        float z = fmaf(lds[SW_WT1 + 2 * k], xi,
                       fmaf(lds[SW_WT1 + 2 * k + 1], tt, lds[SW_BT1 + k]));
        lds[H1V_ + k * 64 + p] = tanhf(z);
    }

    // ---- Phase B: trunk layer-2 jets; Wt2^T streamed through LDS in 4 chunks ----
    float a0[16], a1[16], a2[16], a3[16];
#pragma unroll
    for (int jj = 0; jj < 16; ++jj) { a0[jj] = 0.f; a1[jj] = 0.f; a2[jj] = 0.f; a3[jj] = 0.f; }
    for (int c = 0; c < 4; ++c) {
        __syncthreads();   // c=0: phase A done; c>0: previous sweep done with SCR_
        {
            const float4* src = (const float4*)(ws + 512 + c * 4096);
            float4* dst = (float4*)(lds + SCR_);
            dst[tid] = src[tid];
            dst[tid + 512] = src[tid + 512];
        }
        __syncthreads();
#pragma unroll 1
        for (int kl = 0; kl < 32; ++kl) {
            int k = c * 32 + kl;
            float v = lds[H1V_ + k * 64 + p];
            float w = lds[SW_WT1 + 2 * k];   // uniform -> LDS broadcast
            float s = 1.f - v * v;
            float f2 = -2.f * v * s;
            float f3 = 2.f * s * (2.f * v * v - s);
            float w2 = w * w;
            float d1 = s * w;
            float d2 = f2 * w2;
            float d3 = f3 * w2 * w;
            const float4* wr = (const float4*)(lds + SCR_ + kl * 128 + slice * 16);
            float4 wv0 = wr[0], wv1 = wr[1], wv2 = wr[2], wv3 = wr[3];
            const float wf[16] = {wv0.x, wv0.y, wv0.z, wv0.w, wv1.x, wv1.y, wv1.z, wv1.w,
                                  wv2.x, wv2.y, wv2.z, wv2.w, wv3.x, wv3.y, wv3.z, wv3.w};
#pragma unroll
            for (int jj = 0; jj < 16; ++jj) {
                float wjk = wf[jj];
                a0[jj] = fmaf(wjk, v, a0[jj]);
                a1[jj] = fmaf(wjk, d1, a1[jj]);
                a2[jj] = fmaf(wjk, d2, a2[jj]);
                a3[jj] = fmaf(wjk, d3, a3[jj]);
            }
        }
    }
    // finalize this slice's u-jet partials
    float u0 = 0.f, u1 = 0.f, u2 = 0.f, u3 = 0.f;
#pragma unroll
    for (int jj = 0; jj < 16; ++jj) {
        int j = slice * 16 + jj;
        float z0 = a0[jj] + lds[SW_BT2 + j];
        float z1 = a1[jj], z2 = a2[jj], z3 = a3[jj];
        float v = tanhf(z0);
        float s = 1.f - v * v;
        float f2 = -2.f * v * s;
        float f3 = 2.f * s * (2.f * v * v - s);
        float cj = lds[SW_CVEC + j];
        u0 = fmaf(cj, v, u0);
        u1 = fmaf(cj, s * z1, u1);
        u2 = fmaf(cj, f2 * z1 * z1 + s * z2, u2);
        u3 = fmaf(cj, f3 * z1 * z1 * z1 + 3.f * f2 * z1 * z2 + s * z3, u3);
    }
    __syncthreads();   // all sweeps done -> SCR_ reusable as RED planes
    lds[SCR_ + 0 * 512 + slice * 64 + p] = u0;   // plane-major: conflict-free
    lds[SCR_ + 1 * 512 + slice * 64 + p] = u1;
    lds[SCR_ + 2 * 512 + slice * 64 + p] = u2;
    lds[SCR_ + 3 * 512 + slice * 64 + p] = u3;
    __syncthreads();

    // ---- reduce u jets across slices (threads 0..63) ----
    if (tid < 64) {
        float r0 = u_const, r1 = 0.f, r2 = 0.f, r3 = 0.f;
#pragma unroll
        for (int s = 0; s < 8; ++s) {
            r0 += lds[SCR_ + 0 * 512 + s * 64 + tid];
            r1 += lds[SCR_ + 1 * 512 + s * 64 + tid];
            r2 += lds[SCR_ + 2 * 512 + s * 64 + tid];
            r3 += lds[SCR_ + 3 * 512 + s * 64 + tid];
        }
        lds[UREDP + 0 * 64 + tid] = r0;
        lds[UREDP + 1 * 64 + tid] = r1;
        lds[UREDP + 2 * 64 + tid] = r2;
        lds[UREDP + 3 * 64 + tid] = r3;
    }
    __syncthreads();   // RED consumed -> SCR_ reusable for We2t

    // ---- Phase C part 1: stage We2t + energy layer-1 tanh values ----
    {
        const float4* src = (const float4*)(ws + 16896);
        float4* dst = (float4*)(lds + SCR_);
        dst[tid] = src[tid];
        dst[tid + 512] = src[tid + 512];
    }
    const float y = lds[UREDP + 0 * 64 + p];
    const float z = lds[UREDP + 1 * 64 + p];
#pragma unroll
    for (int q = 0; q < 8; ++q) {
        int ii = slice * 8 + q;
        float g = fmaf(lds[SW_WE1 + 2 * ii], y,
                       fmaf(lds[SW_WE1 + 2 * ii + 1], z, lds[SW_BE1 + ii]));
        lds[H1V_ + ii * 64 + p] = tanhf(g);
    }
    __syncthreads();

    // ---- Phase C part 2: energy layer-2 jets, this slice's 8 m's ----
    {
        float A0[8], A1[8], A2[8], A3[8], A4[8], A5[8], A6[8], A7[8], A8[8];
#pragma unroll
        for (int mm = 0; mm < 8; ++mm) {
            A0[mm] = 0.f; A1[mm] = 0.f; A2[mm] = 0.f; A3[mm] = 0.f; A4[mm] = 0.f;
            A5[mm] = 0.f; A6[mm] = 0.f; A7[mm] = 0.f; A8[mm] = 0.f;
        }
#pragma unroll 1
        for (int ii = 0; ii < 64; ++ii) {
            float v = lds[H1V_ + ii * 64 + p];
            float w0 = lds[SW_WE1 + 2 * ii];       // uniform -> broadcast
            float w1 = lds[SW_WE1 + 2 * ii + 1];
            float s = 1.f - v * v;
            float f2 = -2.f * v * s;
            float f3 = 2.f * s * (2.f * v * v - s);
            float w00 = w0 * w0, w01 = w0 * w1, w11 = w1 * w1;
            float j1 = s * w0, j2 = s * w1;
            float j3 = f2 * w00, j4 = f2 * w01, j5 = f2 * w11;
            float j6 = f3 * w00 * w1, j7 = f3 * w01 * w1, j8 = f3 * w11 * w1;
            const float4* wr = (const float4*)(lds + SCR_ + ii * 64 + slice * 8);
            float4 wv0 = wr[0], wv1 = wr[1];
            const float wf[8] = {wv0.x, wv0.y, wv0.z, wv0.w, wv1.x, wv1.y, wv1.z, wv1.w};
#pragma unroll
            for (int mm = 0; mm < 8; ++mm) {
                float wmi = wf[mm];
                A0[mm] = fmaf(wmi, v,  A0[mm]);
                A1[mm] = fmaf(wmi, j1, A1[mm]);
                A2[mm] = fmaf(wmi, j2, A2[mm]);
                A3[mm] = fmaf(wmi, j3, A3[mm]);
                A4[mm] = fmaf(wmi, j4, A4[mm]);
                A5[mm] = fmaf(wmi, j5, A5[mm]);
                A6[mm] = fmaf(wmi, j6, A6[mm]);
                A7[mm] = fmaf(wmi, j7, A7[mm]);
                A8[mm] = fmaf(wmi, j8, A8[mm]);
            }
        }
        float Fyy = 0.f, Fyz = 0.f, Fzz = 0.f, Fyyz = 0.f, Fyzz = 0.f, Fzzz = 0.f;
#pragma unroll
        for (int mm = 0; mm < 8; ++mm) {
            int m = slice * 8 + mm;
            float G0 = A0[mm] + lds[SW_BE2 + m];
            float v = tanhf(G0);
            float s = 1.f - v * v;
            float f2 = -2.f * v * s;
            float f3 = 2.f * s * (2.f * v * v - s);
            float Gy = A1[mm], Gz = A2[mm];
            float Gyy = A3[mm], Gyz = A4[mm], Gzz = A5[mm];
            float Hyy = f2 * Gy * Gy + s * Gyy;
            float Hyz = f2 * Gy * Gz + s * Gyz;
            float Hzz = f2 * Gz * Gz + s * Gzz;
            float Hyyz = f3 * Gy * Gy * Gz + f2 * (Gyy * Gz + 2.f * Gyz * Gy) + s * A6[mm];
            float Hyzz = f3 * Gy * Gz * Gz + f2 * (2.f * Gyz * Gz + Gzz * Gy) + s * A7[mm];
            float Hzzz = f3 * Gz * Gz * Gz + 3.f * f2 * Gzz * Gz + s * A8[mm];
            float w3 = lds[SW_WE3 + m];
            Fyy  = fmaf(w3, Hyy,  Fyy);
            Fyz  = fmaf(w3, Hyz,  Fyz);
            Fzz  = fmaf(w3, Hzz,  Fzz);
            Fyyz = fmaf(w3, Hyyz, Fyyz);
            Fyzz = fmaf(w3, Hyzz, Fyzz);
            Fzzz = fmaf(w3, Hzzz, Fzzz);
        }
        lds[FREDP + 0 * 512 + slice * 64 + p] = Fyy;   // plane-major: conflict-free
        lds[FREDP + 1 * 512 + slice * 64 + p] = Fyz;
        lds[FREDP + 2 * 512 + slice * 64 + p] = Fzz;
        lds[FREDP + 3 * 512 + slice * 64 + p] = Fyyz;
        lds[FREDP + 4 * 512 + slice * 64 + p] = Fyzz;
        lds[FREDP + 5 * 512 + slice * 64 + p] = Fzzz;
    }
    __syncthreads();

    // ---- reduce F partials + combine (threads 0..63) ----
    if (tid < 64) {
        float F[6] = {0.f, 0.f, 0.f, 0.f, 0.f, 0.f};
#pragma unroll
        for (int s = 0; s < 8; ++s) {
#pragma unroll
            for (int q = 0; q < 6; ++q) F[q] += lds[FREDP + q * 512 + s * 64 + tid];
        }
        float u1r = lds[UREDP + 1 * 64 + tid];
        float u2r = lds[UREDP + 2 * 64 + tid];
        float u3r = lds[UREDP + 3 * 64 + tid];
        float F_yx  = F[0] * u1r + F[1] * u2r;
        float F_zxx = F[1] * u2r + F[2] * u3r + F[3] * u1r * u1r
                    + 2.f * F[4] * u1r * u2r + F[5] * u2r * u2r;
        out[bx * 64 + tid] = F_zxx - F_yx;
    }
}

extern "C" void kernel_launch(void* const* d_in, const int* in_sizes, int n_in,
                              void* d_out, int out_size, void* d_ws, size_t ws_size,
                              hipStream_t stream) {
    const float* a   = (const float*)d_in[0];
    const float* x   = (const float*)d_in[1];
    const float* t   = (const float*)d_in[2];
    const float* Wb  = (const float*)d_in[3];
    const float* bb  = (const float*)d_in[4];
    const float* Wt1 = (const float*)d_in[5];
    const float* bt1 = (const float*)d_in[6];
    const float* Wt2 = (const float*)d_in[7];
    const float* bt2 = (const float*)d_in[8];
    const float* Wt3 = (const float*)d_in[9];
    const float* bt3 = (const float*)d_in[10];
    const float* We1 = (const float*)d_in[11];
    const float* be1 = (const float*)d_in[12];
    const float* We2 = (const float*)d_in[13];
    const float* be2 = (const float*)d_in[14];
    const float* We3 = (const float*)d_in[15];

    float* ws = (float*)d_ws;
    float* out = (float*)d_out;

    prep1_k<<<64, 256, 0, stream>>>(Wt2, We2, ws);
    // DIAGNOSTIC round: gemv x4 (z-replicas), point x4 (blockIdx.x & 511) so
    // both exceed the 160us poison fills and surface in the top-5 counters.
    gemv_k<<<dim3(128, 32, 4), 256, 0, stream>>>(Wb, a, ws);
    prep2_k<<<1, 128, 0, stream>>>(ws, bb, Wt3, bt3, ws);
    point_k<<<4 * (NXP / 64), 512, 0, stream>>>(x, t, Wt1, bt1, bt2, We1, be1, be2,
                                                We3, ws, out);
}

// Round 5
// 460.784 us; speedup vs baseline: 1.8461x; 1.8461x over previous
//
#include <hip/hip_runtime.h>
#include <cmath>

#define MP1 524288
#define NXP 32768

typedef float vfloat4 __attribute__((ext_vector_type(4)));

// ws layout (float offsets):
//   [0,4096)        gemv partials [row*32+chunk] (plain stores, no zero-init)
//   [4096,4224)     cvec = Wt3^T (b+bb)
//   [4224]          u_const = dot(b, bt3)
//   [8192,24576)    WT2t[k*128+j] = Wt2[j*128+k]
//   [24576,28672)   WE2t[i*64+m]  = We2[m*64+i]
#define PART_   0
#define CVEC_   4096
#define UCONST_ 4224
#define WT2T_   8192
#define WE2T_   24576

// tanh via native exp2 + rcp: 6 VALU ops vs ~20 for libm tanhf. Clamp +-20
// keeps exp2 finite (tanh saturates to 1.0f beyond ~9 anyway). Abs err ~1e-7,
// invisible under the 0.125 fp32-accumulation baseline absmax.
__device__ __forceinline__ float tanh_fast(float x) {
    x = fminf(20.f, fmaxf(-20.f, x));
    float t = exp2f(x * 2.8853900817779268f);       // e^(2x)
    return (t - 1.f) * __builtin_amdgcn_rcpf(t + 1.f);
}

// R4 diagnostic: gemv ~50-60us (268MB stream, near HBM floor). Partials to ws,
// no atomics -> prep1's b_acc zeroing kernel is eliminated (4 launches -> 3).
__global__ __launch_bounds__(256) void gemv_k(const float* __restrict__ Wb,
                                              const float* __restrict__ a,
                                              float* __restrict__ ws) {
    const int row = blockIdx.x;
    const int chunk = blockIdx.y;
    const int t = threadIdx.x;
    size_t base = (size_t)row * MP1 + (size_t)chunk * 16384;
    const vfloat4* W4 = (const vfloat4*)(Wb + base);
    const float4* A4 = (const float4*)(a + (size_t)chunk * 16384);
    float sum = 0.0f;
#pragma unroll
    for (int it = 0; it < 16; ++it) {
        vfloat4 w = __builtin_nontemporal_load(&W4[t + it * 256]);
        float4 av = A4[t + it * 256];
        sum += w[0] * av.x + w[1] * av.y + w[2] * av.z + w[3] * av.w;
    }
#pragma unroll
    for (int off = 32; off > 0; off >>= 1) sum += __shfl_down(sum, off, 64);
    __shared__ float red[4];
    int wid = t >> 6;
    if ((t & 63) == 0) red[wid] = sum;
    __syncthreads();
    if (t == 0) ws[PART_ + row * 32 + chunk] = red[0] + red[1] + red[2] + red[3];
}

// merged prep: block 0 reduces partials -> b, cvec, u_const; blocks 1..64 do
// the two weight transposes. One launch instead of two.
__global__ __launch_bounds__(256) void prep_k(const float* __restrict__ bb,
                                              const float* __restrict__ Wt2,
                                              const float* __restrict__ We2,
                                              const float* __restrict__ Wt3,
                                              const float* __restrict__ bt3,
                                              float* __restrict__ ws) {
    const int tid = threadIdx.x;
    if (blockIdx.x == 0) {
        __shared__ float sh[128];
        __shared__ float red[2];
        if (tid < 128) {
            float b = bb[tid];
            const float* part = ws + PART_ + tid * 32;
#pragma unroll
            for (int c = 0; c < 32; ++c) b += part[c];
            sh[tid] = b;
        }
        __syncthreads();
        if (tid < 128) {
            float cv = 0.f;
            for (int j = 0; j < 128; ++j) cv = fmaf(sh[j], Wt3[j * 128 + tid], cv);
            ws[CVEC_ + tid] = cv;
            float p = sh[tid] * bt3[tid];
#pragma unroll
            for (int off = 32; off > 0; off >>= 1) p += __shfl_down(p, off, 64);
            if ((tid & 63) == 0) red[tid >> 6] = p;
        }
        __syncthreads();
        if (tid == 0) ws[UCONST_] = red[0] + red[1];
    } else {
        int idx = (blockIdx.x - 1) * 256 + tid;     // 0..16383
        int j = idx >> 7, k = idx & 127;
        ws[WT2T_ + k * 128 + j] = Wt2[idx];
        if (idx < 4096) {
            int m = idx >> 6, i2 = idx & 63;
            ws[WE2T_ + i2 * 64 + m] = We2[idx];
        }
    }
}

// point_k: VALU-issue-bound (R4: VALUBusy 90.6%, 0 bank conflicts, no spills).
// This round trims instruction count: (a) phase-B aux 12->9 ops/k via constant
// folding (-2/+2 of f2/f3 moved to the 16-wide finalize) and 2v^2-s == 2-3s;
// (b) phase-C aux ~21->12 ops/ii via a per-ii weight-product LDS table (w00,
// w01, w11, w00w1, w01w1, w11w1 computed ONCE at stage time, previously
// recomputed by every thread every ii); (c) tanh_fast (6 ops vs ~20).
// LDS (floats):
#define SW_WT1 0        // 256: Wt1 interleaved [k][2]
#define SW_BT1 256      // 128
#define SW_BT2 384      // 128
#define SW_CVEC 512     // 128
#define SW_WE1X 640     // 512: per-ii {w0,w1,w00,w01,w11,w00w1,w01w1,w11w1}
#define SW_BE1 1152     // 64
#define SW_BE2 1216     // 64
#define SW_WE3 1280     // 64
#define UREDP 1344      // 256: reduced u jets, plane-major [r*64+p]
#define H1V_ 1600       // 8192: trunk h1 [k*64+p]; phase C reuses [0,4096) for
                        //       energy h; FRED planes follow
#define FREDP (H1V_ + 4096)
#define SCR_ 9792       // 4096: Wt2t 32-k chunk (B) -> RED planes -> We2t (C)
#define LDSF 13888      // 55,552 B -> 2 blocks/CU (unchanged occupancy)

__global__ __launch_bounds__(512, 4) void point_k(const float* __restrict__ x,
                                                  const float* __restrict__ tptr,
                                                  const float* __restrict__ Wt1,
                                                  const float* __restrict__ bt1,
                                                  const float* __restrict__ bt2,
                                                  const float* __restrict__ We1,
                                                  const float* __restrict__ be1,
                                                  const float* __restrict__ be2,
                                                  const float* __restrict__ We3,
                                                  const float* __restrict__ ws,
                                                  float* __restrict__ out) {
    __shared__ __align__(16) float lds[LDSF];
    const int tid = threadIdx.x;
    const int p = tid & 63;
    const int slice = __builtin_amdgcn_readfirstlane(tid >> 6);
    const int i = blockIdx.x * 64 + p;
    const float xi = x[i];
    const float tt = tptr[0];
    const float u_const = ws[UCONST_];

    // ---- stage small weights + per-ii energy weight products ----
    if (tid < 256) lds[SW_WT1 + tid] = Wt1[tid];
    else if (tid < 384) lds[SW_BT1 + tid - 256] = bt1[tid - 256];
    else lds[SW_BT2 + tid - 384] = bt2[tid - 384];
    if (tid < 128) lds[SW_CVEC + tid] = ws[CVEC_ + tid];
    else if (tid < 192) lds[SW_BE1 + tid - 128] = be1[tid - 128];
    else if (tid < 256) lds[SW_BE2 + tid - 192] = be2[tid - 192];
    else if (tid < 320) lds[SW_WE3 + tid - 256] = We3[tid - 256];
    else if (tid < 384) {
        int ii = tid - 320;
        float w0 = We1[2 * ii], w1 = We1[2 * ii + 1];
        float w00 = w0 * w0, w01 = w0 * w1, w11 = w1 * w1;
        float* X = lds + SW_WE1X + ii * 8;
        X[0] = w0; X[1] = w1; X[2] = w00; X[3] = w01; X[4] = w11;
        X[5] = w00 * w1; X[6] = w01 * w1; X[7] = w11 * w1;
    }
    __syncthreads();

    // ---- Phase A: trunk layer-1 tanh values (16 k's per thread) ----
#pragma unroll
    for (int q = 0; q < 16; ++q) {
        int k = slice * 16 + q;
        float z = fmaf(lds[SW_WT1 + 2 * k], xi,
                       fmaf(lds[SW_WT1 + 2 * k + 1], tt, lds[SW_BT1 + k]));
        lds[H1V_ + k * 64 + p] = tanh_fast(z);
    }

    // ---- Phase B: trunk layer-2 jets; Wt2^T streamed through LDS in 4 chunks ----
    // Accumulate with SCALED operands: a2' uses v*s*w^2 (true d2 = -2*a2'),
    // a3' uses s*(2-3s)*w^3 (true d3 = 2*a3'); constants folded into finalize.
    float a0[16], a1[16], a2[16], a3[16];
#pragma unroll
    for (int jj = 0; jj < 16; ++jj) { a0[jj] = 0.f; a1[jj] = 0.f; a2[jj] = 0.f; a3[jj] = 0.f; }
    for (int c = 0; c < 4; ++c) {
        __syncthreads();   // c=0: phase A done; c>0: previous sweep done with SCR_
        {
            const float4* src = (const float4*)(ws + WT2T_ + c * 4096);
            float4* dst = (float4*)(lds + SCR_);
            dst[tid] = src[tid];
            dst[tid + 512] = src[tid + 512];
        }
        __syncthreads();
#pragma unroll 1
        for (int kl = 0; kl < 32; ++kl) {
            int k = c * 32 + kl;
            float v = lds[H1V_ + k * 64 + p];
            float w = lds[SW_WT1 + 2 * k];          // uniform -> LDS broadcast
            float s = fmaf(-v, v, 1.f);
            float t2 = v * s;                        // f2 = -2*t2
            float m = fmaf(-3.f, s, 2.f);            // 2v^2-s == 2-3s
            float sm = s * m;                        // f3 = 2*sm
            float w2 = w * w, w3 = w2 * w;
            float d1 = s * w;
            float d2 = t2 * w2;
            float d3 = sm * w3;
            const float4* wr = (const float4*)(lds + SCR_ + kl * 128 + slice * 16);
            float4 wv0 = wr[0], wv1 = wr[1], wv2 = wr[2], wv3 = wr[3];
            const float wf[16] = {wv0.x, wv0.y, wv0.z, wv0.w, wv1.x, wv1.y, wv1.z, wv1.w,
                                  wv2.x, wv2.y, wv2.z, wv2.w, wv3.x, wv3.y, wv3.z, wv3.w};
#pragma unroll
            for (int jj = 0; jj < 16; ++jj) {
                float wjk = wf[jj];
                a0[jj] = fmaf(wjk, v, a0[jj]);
                a1[jj] = fmaf(wjk, d1, a1[jj]);
                a2[jj] = fmaf(wjk, d2, a2[jj]);
                a3[jj] = fmaf(wjk, d3, a3[jj]);
            }
        }
    }
    // finalize this slice's u-jet partials (scale fixups applied here)
    float u0 = 0.f, u1 = 0.f, u2 = 0.f, u3 = 0.f;
#pragma unroll
    for (int jj = 0; jj < 16; ++jj) {
        int j = slice * 16 + jj;
        float z0 = a0[jj] + lds[SW_BT2 + j];
        float z1 = a1[jj], z2 = -2.f * a2[jj], z3 = 2.f * a3[jj];
        float v = tanh_fast(z0);
        float s = 1.f - v * v;
        float f2 = -2.f * v * s;
        float f3 = 2.f * s * (2.f * v * v - s);
        float cj = lds[SW_CVEC + j];
        u0 = fmaf(cj, v, u0);
        u1 = fmaf(cj, s * z1, u1);
        u2 = fmaf(cj, f2 * z1 * z1 + s * z2, u2);
        u3 = fmaf(cj, f3 * z1 * z1 * z1 + 3.f * f2 * z1 * z2 + s * z3, u3);
    }
    __syncthreads();   // all sweeps done -> SCR_ reusable as RED planes
    lds[SCR_ + 0 * 512 + slice * 64 + p] = u0;   // plane-major: conflict-free
    lds[SCR_ + 1 * 512 + slice * 64 + p] = u1;
    lds[SCR_ + 2 * 512 + slice * 64 + p] = u2;
    lds[SCR_ + 3 * 512 + slice * 64 + p] = u3;
    __syncthreads();

    // ---- reduce u jets across slices (threads 0..63) ----
    if (tid < 64) {
        float r0 = u_const, r1 = 0.f, r2 = 0.f, r3 = 0.f;
#pragma unroll
        for (int s = 0; s < 8; ++s) {
            r0 += lds[SCR_ + 0 * 512 + s * 64 + tid];
            r1 += lds[SCR_ + 1 * 512 + s * 64 + tid];
            r2 += lds[SCR_ + 2 * 512 + s * 64 + tid];
            r3 += lds[SCR_ + 3 * 512 + s * 64 + tid];
        }
        lds[UREDP + 0 * 64 + tid] = r0;
        lds[UREDP + 1 * 64 + tid] = r1;
        lds[UREDP + 2 * 64 + tid] = r2;
        lds[UREDP + 3 * 64 + tid] = r3;
    }
    __syncthreads();   // RED consumed -> SCR_ reusable for We2t

    // ---- Phase C part 1: stage We2t + energy layer-1 tanh values ----
    {
        const float4* src = (const float4*)(ws + WE2T_);
        float4* dst = (float4*)(lds + SCR_);
        dst[tid] = src[tid];
        dst[tid + 512] = src[tid + 512];
    }
    const float y = lds[UREDP + 0 * 64 + p];
    const float z = lds[UREDP + 1 * 64 + p];
#pragma unroll
    for (int q = 0; q < 8; ++q) {
        int ii = slice * 8 + q;
        float g = fmaf(lds[SW_WE1X + ii * 8], y,
                       fmaf(lds[SW_WE1X + ii * 8 + 1], z, lds[SW_BE1 + ii]));
        lds[H1V_ + ii * 64 + p] = tanh_fast(g);
    }
    __syncthreads();

    // ---- Phase C part 2: energy layer-2 jets; scaled accumulators:
    // A3..A5 accumulate (v*s)*wprod  (true G.. = -2*A),
    // A6..A8 accumulate (s*(2-3s))*wprod (true = 2*A); fixups at finalize.
    {
        float A0[8], A1[8], A2[8], A3[8], A4[8], A5[8], A6[8], A7[8], A8[8];
#pragma unroll
        for (int mm = 0; mm < 8; ++mm) {
            A0[mm] = 0.f; A1[mm] = 0.f; A2[mm] = 0.f; A3[mm] = 0.f; A4[mm] = 0.f;
            A5[mm] = 0.f; A6[mm] = 0.f; A7[mm] = 0.f; A8[mm] = 0.f;
        }
#pragma unroll 1
        for (int ii = 0; ii < 64; ++ii) {
            float v = lds[H1V_ + ii * 64 + p];
            const float4* xw = (const float4*)(lds + SW_WE1X + ii * 8);  // uniform
            float4 xa = xw[0], xb = xw[1];  // {w0,w1,w00,w01},{w11,w00w1,w01w1,w11w1}
            float s = fmaf(-v, v, 1.f);
            float t2 = v * s;
            float m = fmaf(-3.f, s, 2.f);
            float sm = s * m;
            float j1 = s * xa.x, j2 = s * xa.y;
            float j3 = t2 * xa.z, j4 = t2 * xa.w, j5 = t2 * xb.x;
            float j6 = sm * xb.y, j7 = sm * xb.z, j8 = sm * xb.w;
            const float4* wr = (const float4*)(lds + SCR_ + ii * 64 + slice * 8);
            float4 wv0 = wr[0], wv1 = wr[1];
            const float wf[8] = {wv0.x, wv0.y, wv0.z, wv0.w, wv1.x, wv1.y, wv1.z, wv1.w};
#pragma unroll
            for (int mm = 0; mm < 8; ++mm) {
                float wmi = wf[mm];
                A0[mm] = fmaf(wmi, v,  A0[mm]);
                A1[mm] = fmaf(wmi, j1, A1[mm]);
                A2[mm] = fmaf(wmi, j2, A2[mm]);
                A3[mm] = fmaf(wmi, j3, A3[mm]);
                A4[mm] = fmaf(wmi, j4, A4[mm]);
                A5[mm] = fmaf(wmi, j5, A5[mm]);
                A6[mm] = fmaf(wmi, j6, A6[mm]);
                A7[mm] = fmaf(wmi, j7, A7[mm]);
                A8[mm] = fmaf(wmi, j8, A8[mm]);
            }
        }
        float Fyy = 0.f, Fyz = 0.f, Fzz = 0.f, Fyyz = 0.f, Fyzz = 0.f, Fzzz = 0.f;
#pragma unroll
        for (int mm = 0; mm < 8; ++mm) {
            int m = slice * 8 + mm;
            float G0 = A0[mm] + lds[SW_BE2 + m];
            float v = tanh_fast(G0);
            float s = 1.f - v * v;
            float f2 = -2.f * v * s;
            float f3 = 2.f * s * (2.f * v * v - s);
            float Gy = A1[mm], Gz = A2[mm];
            float Gyy = -2.f * A3[mm], Gyz = -2.f * A4[mm], Gzz = -2.f * A5[mm];
            float Gyyz = 2.f * A6[mm], Gyzz = 2.f * A7[mm], Gzzz = 2.f * A8[mm];
            float Hyy = f2 * Gy * Gy + s * Gyy;
            float Hyz = f2 * Gy * Gz + s * Gyz;
            float Hzz = f2 * Gz * Gz + s * Gzz;
            float Hyyz = f3 * Gy * Gy * Gz + f2 * (Gyy * Gz + 2.f * Gyz * Gy) + s * Gyyz;
            float Hyzz = f3 * Gy * Gz * Gz + f2 * (2.f * Gyz * Gz + Gzz * Gy) + s * Gyzz;
            float Hzzz = f3 * Gz * Gz * Gz + 3.f * f2 * Gzz * Gz + s * Gzzz;
            float w3 = lds[SW_WE3 + m];
            Fyy  = fmaf(w3, Hyy,  Fyy);
            Fyz  = fmaf(w3, Hyz,  Fyz);
            Fzz  = fmaf(w3, Hzz,  Fzz);
            Fyyz = fmaf(w3, Hyyz, Fyyz);
            Fyzz = fmaf(w3, Hyzz, Fyzz);
            Fzzz = fmaf(w3, Hzzz, Fzzz);
        }
        lds[FREDP + 0 * 512 + slice * 64 + p] = Fyy;   // plane-major: conflict-free
        lds[FREDP + 1 * 512 + slice * 64 + p] = Fyz;
        lds[FREDP + 2 * 512 + slice * 64 + p] = Fzz;
        lds[FREDP + 3 * 512 + slice * 64 + p] = Fyyz;
        lds[FREDP + 4 * 512 + slice * 64 + p] = Fyzz;
        lds[FREDP + 5 * 512 + slice * 64 + p] = Fzzz;
    }
    __syncthreads();

    // ---- reduce F partials + combine (threads 0..63) ----
    if (tid < 64) {
        float F[6] = {0.f, 0.f, 0.f, 0.f, 0.f, 0.f};
#pragma unroll
        for (int s = 0; s < 8; ++s) {
#pragma unroll
            for (int q = 0; q < 6; ++q) F[q] += lds[FREDP + q * 512 + s * 64 + tid];
        }
        float u1r = lds[UREDP + 1 * 64 + tid];
        float u2r = lds[UREDP + 2 * 64 + tid];
        float u3r = lds[UREDP + 3 * 64 + tid];
        float F_yx  = F[0] * u1r + F[1] * u2r;
        float F_zxx = F[1] * u2r + F[2] * u3r + F[3] * u1r * u1r
                    + 2.f * F[4] * u1r * u2r + F[5] * u2r * u2r;
        out[blockIdx.x * 64 + tid] = F_zxx - F_yx;
    }
}

extern "C" void kernel_launch(void* const* d_in, const int* in_sizes, int n_in,
                              void* d_out, int out_size, void* d_ws, size_t ws_size,
                              hipStream_t stream) {
    const float* a   = (const float*)d_in[0];
    const float* x   = (const float*)d_in[1];
    const float* t   = (const float*)d_in[2];
    const float* Wb  = (const float*)d_in[3];
    const float* bb  = (const float*)d_in[4];
    const float* Wt1 = (const float*)d_in[5];
    const float* bt1 = (const float*)d_in[6];
    const float* Wt2 = (const float*)d_in[7];
    const float* bt2 = (const float*)d_in[8];
    const float* Wt3 = (const float*)d_in[9];
    const float* bt3 = (const float*)d_in[10];
    const float* We1 = (const float*)d_in[11];
    const float* be1 = (const float*)d_in[12];
    const float* We2 = (const float*)d_in[13];
    const float* be2 = (const float*)d_in[14];
    const float* We3 = (const float*)d_in[15];

    float* ws = (float*)d_ws;
    float* out = (float*)d_out;

    // 3 launches (was 4): gemv writes partials (no atomics) -> merged prep
    // (block 0: reduce/cvec/u_const; blocks 1..64: transposes) -> point.
    gemv_k<<<dim3(128, 32), 256, 0, stream>>>(Wb, a, ws);
    prep_k<<<65, 256, 0, stream>>>(bb, Wt2, We2, Wt3, bt3, ws);
    point_k<<<NXP / 64, 512, 0, stream>>>(x, t, Wt1, bt1, bt2, We1, be1, be2, We3,
                                          ws, out);
}

// Round 6
// 458.707 us; speedup vs baseline: 1.8545x; 1.0045x over previous
//
#include <hip/hip_runtime.h>
#include <cmath>

#define MP1 524288
#define NXP 32768

typedef float vfloat4 __attribute__((ext_vector_type(4)));

// ws layout (float offsets):
//   [0,4096)        gemv partials [row*32+chunk]
//   [8192,24576)    WT2t[k*128+j] = Wt2[j*128+k]
//   [24576,28672)   WE2t[i*64+m]  = We2[m*64+i]
//   [28672,45056)   WT3t[k*128+j] = Wt3[j*128+k]
#define PART_   0
#define WT2T_   8192
#define WE2T_   24576
#define WT3T_   28672

// tanh via native exp2 + rcp: 6 VALU ops vs ~20 for libm tanhf.
__device__ __forceinline__ float tanh_fast(float x) {
    x = fminf(20.f, fmaxf(-20.f, x));
    float t = exp2f(x * 2.8853900817779268f);       // e^(2x)
    return (t - 1.f) * __builtin_amdgcn_rcpf(t + 1.f);
}

// gemv (~45us, near 43us HBM floor for the 268MB Wb stream) + tail blocks
// (y>=32) that do the three weight transposes concurrently with the stream.
// 2 launches total: prep_k is gone (reduction/cvec/u_const inlined in point_k).
__global__ __launch_bounds__(256) void gemv_k(const float* __restrict__ Wb,
                                              const float* __restrict__ a,
                                              const float* __restrict__ Wt2,
                                              const float* __restrict__ We2,
                                              const float* __restrict__ Wt3,
                                              float* __restrict__ ws) {
    const int y = blockIdx.y;
    const int tid = threadIdx.x;
    if (y >= 32) {                       // transpose tail
        int idx = blockIdx.x * 256 + tid;
        if (y == 32) {
            if (idx < 16384) {
                int j = idx >> 7, k = idx & 127;
                ws[WT2T_ + k * 128 + j] = Wt2[idx];
            } else if (idx < 20480) {
                int e = idx - 16384;
                int m = e >> 6, i2 = e & 63;
                ws[WE2T_ + i2 * 64 + m] = We2[e];
            }
        } else {
            if (idx < 16384) {
                int j = idx >> 7, k = idx & 127;
                ws[WT3T_ + k * 128 + j] = Wt3[idx];
            }
        }
        return;
    }
    const int row = blockIdx.x;
    const int chunk = y;
    size_t base = (size_t)row * MP1 + (size_t)chunk * 16384;
    const vfloat4* W4 = (const vfloat4*)(Wb + base);
    const float4* A4 = (const float4*)(a + (size_t)chunk * 16384);
    float sum = 0.0f;
#pragma unroll
    for (int it = 0; it < 16; ++it) {
        vfloat4 w = __builtin_nontemporal_load(&W4[tid + it * 256]);
        float4 av = A4[tid + it * 256];
        sum += w[0] * av.x + w[1] * av.y + w[2] * av.z + w[3] * av.w;
    }
#pragma unroll
    for (int off = 32; off > 0; off >>= 1) sum += __shfl_down(sum, off, 64);
    __shared__ float red[4];
    int wid = tid >> 6;
    if ((tid & 63) == 0) red[wid] = sum;
    __syncthreads();
    if (tid == 0) ws[PART_ + row * 32 + chunk] = red[0] + red[1] + red[2] + red[3];
}

// point_k: VALU-issue-bound (R4: VALUBusy 90.6%, 0 bank conflicts, no spills).
// R6: (a) b/cvec/u_const computed per-block (cheap, kills prep launch);
// (b) stage-time {w,w^2,w^3} table removes 2 VALU/k from the B hot loop;
// (c) Wt2t staged in 2x32KB chunks (half the barriers). LDS 74.5KB -> 2/CU.
// LDS (floats):
#define SW_WT1 0        // 256: Wt1 interleaved [k][2]
#define SW_BT1 256      // 128
#define SW_BT2 384      // 128
#define SW_CVEC 512     // 128 (computed in-block)
#define SW_WE1X 640     // 512: per-ii {w0,w1,w00,w01,w11,w00w1,w01w1,w11w1}
#define SW_BE1 1152     // 64
#define SW_BE2 1216     // 64
#define SW_WE3 1280     // 64
#define SW_B 1344       // 128: b = bb + sum(partials)
#define WTAB 1472       // 512: per-k {w, w^2, w^3, 0}
#define REDU 1984       // 16: u_const partial sums
#define UREDP 2000      // 256: reduced u jets, plane-major [r*64+p]
#define H1V_ 2256       // 8192: trunk h1 [k*64+p]; phase C reuses [0,4096)
#define FREDP (H1V_ + 4096)   // 3072: F partial planes
#define SCR_ 10448      // 8192: Wt2t 64-k chunk (B) -> RED planes -> We2t (C)
#define LDSF 18640      // 74,560 B -> 2 blocks/CU

__global__ __launch_bounds__(512, 4) void point_k(const float* __restrict__ x,
                                                  const float* __restrict__ tptr,
                                                  const float* __restrict__ Wt1,
                                                  const float* __restrict__ bt1,
                                                  const float* __restrict__ bt2,
                                                  const float* __restrict__ We1,
                                                  const float* __restrict__ be1,
                                                  const float* __restrict__ be2,
                                                  const float* __restrict__ We3,
                                                  const float* __restrict__ bb,
                                                  const float* __restrict__ bt3,
                                                  const float* __restrict__ ws,
                                                  float* __restrict__ out) {
    __shared__ __align__(16) float lds[LDSF];
    const int tid = threadIdx.x;
    const int p = tid & 63;
    const int slice = __builtin_amdgcn_readfirstlane(tid >> 6);
    const int i = blockIdx.x * 64 + p;
    const float xi = x[i];
    const float tt = tptr[0];

    // ---- stage small weights, w-power tables, and b = bb + sum(partials) ----
    if (tid < 256) lds[SW_WT1 + tid] = Wt1[tid];
    else if (tid < 384) lds[SW_BT1 + tid - 256] = bt1[tid - 256];
    else lds[SW_BT2 + tid - 384] = bt2[tid - 384];
    if (tid < 128) {
        float w0 = Wt1[2 * tid];
        float* T = lds + WTAB + tid * 4;
        T[0] = w0; T[1] = w0 * w0; T[2] = w0 * w0 * w0; T[3] = 0.f;
    } else if (tid < 192) lds[SW_BE1 + tid - 128] = be1[tid - 128];
    else if (tid < 256) lds[SW_BE2 + tid - 192] = be2[tid - 192];
    else if (tid < 320) lds[SW_WE3 + tid - 256] = We3[tid - 256];
    else if (tid < 384) {
        int ii = tid - 320;
        float w0 = We1[2 * ii], w1 = We1[2 * ii + 1];
        float w00 = w0 * w0, w01 = w0 * w1, w11 = w1 * w1;
        float* X = lds + SW_WE1X + ii * 8;
        X[0] = w0; X[1] = w1; X[2] = w00; X[3] = w01; X[4] = w11;
        X[5] = w00 * w1; X[6] = w01 * w1; X[7] = w11 * w1;
    } else {
        int j = tid - 384;                       // 0..127
        const float4* P4 = (const float4*)(ws + PART_ + j * 32);
        float b = bb[j];
#pragma unroll
        for (int q = 0; q < 8; ++q) {
            float4 v4 = P4[q];
            b += v4.x; b += v4.y; b += v4.z; b += v4.w;
        }
        lds[SW_B + j] = b;
    }
    __syncthreads();

    // ---- Phase A: trunk layer-1 tanh values (16 k's per thread) ----
#pragma unroll
    for (int q = 0; q < 16; ++q) {
        int k = slice * 16 + q;
        float z = fmaf(lds[SW_WT1 + 2 * k], xi,
                       fmaf(lds[SW_WT1 + 2 * k + 1], tt, lds[SW_BT1 + k]));
        lds[H1V_ + k * 64 + p] = tanh_fast(z);
    }
    // ---- cvec + u_const (threads 0..127, overlapped with phase A of others;
    //      first chunk barrier below makes them visible) ----
    if (tid < 128) {
        float cv = 0.f;
        const float4* W4 = (const float4*)(ws + WT3T_ + tid * 128);
#pragma unroll 4
        for (int q = 0; q < 32; ++q) {
            float4 wv = W4[q];
            cv = fmaf(lds[SW_B + 4 * q + 0], wv.x, cv);
            cv = fmaf(lds[SW_B + 4 * q + 1], wv.y, cv);
            cv = fmaf(lds[SW_B + 4 * q + 2], wv.z, cv);
            cv = fmaf(lds[SW_B + 4 * q + 3], wv.w, cv);
        }
        lds[SW_CVEC + tid] = cv;
        float pk_ = lds[SW_B + tid] * bt3[tid];
#pragma unroll
        for (int off = 32; off > 0; off >>= 1) pk_ += __shfl_down(pk_, off, 64);
        if ((tid & 63) == 0) lds[REDU + (tid >> 6)] = pk_;
    }

    // ---- Phase B: trunk layer-2 jets; Wt2^T streamed in 2x(8192 float) chunks.
    // Scaled accumulators: a2' = v*s*w^2 (d2 = -2a2'), a3' = s*(2-3s)*w^3
    // (d3 = 2a3'); constants folded into the finalize.
    float a0[16], a1[16], a2[16], a3[16];
#pragma unroll
    for (int jj = 0; jj < 16; ++jj) { a0[jj] = 0.f; a1[jj] = 0.f; a2[jj] = 0.f; a3[jj] = 0.f; }
    for (int c = 0; c < 2; ++c) {
        __syncthreads();   // c=0: staging+phaseA+cvec done; c=1: prev sweep done
        {
            const float4* src = (const float4*)(ws + WT2T_ + c * 8192);
            float4* dst = (float4*)(lds + SCR_);
            dst[tid] = src[tid];
            dst[tid + 512] = src[tid + 512];
            dst[tid + 1024] = src[tid + 1024];
            dst[tid + 1536] = src[tid + 1536];
        }
        __syncthreads();
#pragma unroll 1
        for (int kl = 0; kl < 64; ++kl) {
            int k = c * 64 + kl;
            float v = lds[H1V_ + k * 64 + p];
            const float4* wtp = (const float4*)(lds + WTAB + k * 4);  // uniform
            float4 wt = wtp[0];                  // {w, w^2, w^3, 0}
            float s = fmaf(-v, v, 1.f);
            float t2 = v * s;                    // f2 = -2*t2
            float m = fmaf(-3.f, s, 2.f);        // 2v^2-s == 2-3s
            float sm = s * m;                    // f3 = 2*sm
            float d1 = s * wt.x;
            float d2 = t2 * wt.y;
            float d3 = sm * wt.z;
            const float4* wr = (const float4*)(lds + SCR_ + kl * 128 + slice * 16);
            float4 wv0 = wr[0], wv1 = wr[1], wv2 = wr[2], wv3 = wr[3];
            const float wf[16] = {wv0.x, wv0.y, wv0.z, wv0.w, wv1.x, wv1.y, wv1.z, wv1.w,
                                  wv2.x, wv2.y, wv2.z, wv2.w, wv3.x, wv3.y, wv3.z, wv3.w};
#pragma unroll
            for (int jj = 0; jj < 16; ++jj) {
                float wjk = wf[jj];
                a0[jj] = fmaf(wjk, v, a0[jj]);
                a1[jj] = fmaf(wjk, d1, a1[jj]);
                a2[jj] = fmaf(wjk, d2, a2[jj]);
                a3[jj] = fmaf(wjk, d3, a3[jj]);
            }
        }
    }
    // finalize this slice's u-jet partials (scale fixups applied here)
    float u0 = 0.f, u1 = 0.f, u2 = 0.f, u3 = 0.f;
#pragma unroll
    for (int jj = 0; jj < 16; ++jj) {
        int j = slice * 16 + jj;
        float z0 = a0[jj] + lds[SW_BT2 + j];
        float z1 = a1[jj], z2 = -2.f * a2[jj], z3 = 2.f * a3[jj];
        float v = tanh_fast(z0);
        float s = 1.f - v * v;
        float f2 = -2.f * v * s;
        float f3 = 2.f * s * (2.f * v * v - s);
        float cj = lds[SW_CVEC + j];
        u0 = fmaf(cj, v, u0);
        u1 = fmaf(cj, s * z1, u1);
        u2 = fmaf(cj, f2 * z1 * z1 + s * z2, u2);
        u3 = fmaf(cj, f3 * z1 * z1 * z1 + 3.f * f2 * z1 * z2 + s * z3, u3);
    }
    __syncthreads();   // sweeps done -> SCR_ reusable as RED planes
    lds[SCR_ + 0 * 512 + slice * 64 + p] = u0;   // plane-major: conflict-free
    lds[SCR_ + 1 * 512 + slice * 64 + p] = u1;
    lds[SCR_ + 2 * 512 + slice * 64 + p] = u2;
    lds[SCR_ + 3 * 512 + slice * 64 + p] = u3;
    __syncthreads();

    // ---- reduce u jets across slices (threads 0..63) ----
    if (tid < 64) {
        float r0 = lds[REDU] + lds[REDU + 1];    // u_const
        float r1 = 0.f, r2 = 0.f, r3 = 0.f;
#pragma unroll
        for (int s = 0; s < 8; ++s) {
            r0 += lds[SCR_ + 0 * 512 + s * 64 + tid];
            r1 += lds[SCR_ + 1 * 512 + s * 64 + tid];
            r2 += lds[SCR_ + 2 * 512 + s * 64 + tid];
            r3 += lds[SCR_ + 3 * 512 + s * 64 + tid];
        }
        lds[UREDP + 0 * 64 + tid] = r0;
        lds[UREDP + 1 * 64 + tid] = r1;
        lds[UREDP + 2 * 64 + tid] = r2;
        lds[UREDP + 3 * 64 + tid] = r3;
    }
    __syncthreads();   // RED consumed -> SCR_ reusable for We2t

    // ---- Phase C part 1: stage We2t + energy layer-1 tanh values ----
    {
        const float4* src = (const float4*)(ws + WE2T_);
        float4* dst = (float4*)(lds + SCR_);
        dst[tid] = src[tid];
        dst[tid + 512] = src[tid + 512];
    }
    const float y = lds[UREDP + 0 * 64 + p];
    const float z = lds[UREDP + 1 * 64 + p];
#pragma unroll
    for (int q = 0; q < 8; ++q) {
        int ii = slice * 8 + q;
        float g = fmaf(lds[SW_WE1X + ii * 8], y,
                       fmaf(lds[SW_WE1X + ii * 8 + 1], z, lds[SW_BE1 + ii]));
        lds[H1V_ + ii * 64 + p] = tanh_fast(g);
    }
    __syncthreads();

    // ---- Phase C part 2: energy layer-2 jets (scaled accumulators) ----
    {
        float A0[8], A1[8], A2[8], A3[8], A4[8], A5[8], A6[8], A7[8], A8[8];
#pragma unroll
        for (int mm = 0; mm < 8; ++mm) {
            A0[mm] = 0.f; A1[mm] = 0.f; A2[mm] = 0.f; A3[mm] = 0.f; A4[mm] = 0.f;
            A5[mm] = 0.f; A6[mm] = 0.f; A7[mm] = 0.f; A8[mm] = 0.f;
        }
#pragma unroll 1
        for (int ii = 0; ii < 64; ++ii) {
            float v = lds[H1V_ + ii * 64 + p];
            const float4* xw = (const float4*)(lds + SW_WE1X + ii * 8);  // uniform
            float4 xa = xw[0], xb = xw[1];
            float s = fmaf(-v, v, 1.f);
            float t2 = v * s;
            float m = fmaf(-3.f, s, 2.f);
            float sm = s * m;
            float j1 = s * xa.x, j2 = s * xa.y;
            float j3 = t2 * xa.z, j4 = t2 * xa.w, j5 = t2 * xb.x;
            float j6 = sm * xb.y, j7 = sm * xb.z, j8 = sm * xb.w;
            const float4* wr = (const float4*)(lds + SCR_ + ii * 64 + slice * 8);
            float4 wv0 = wr[0], wv1 = wr[1];
            const float wf[8] = {wv0.x, wv0.y, wv0.z, wv0.w, wv1.x, wv1.y, wv1.z, wv1.w};
#pragma unroll
            for (int mm = 0; mm < 8; ++mm) {
                float wmi = wf[mm];
                A0[mm] = fmaf(wmi, v,  A0[mm]);
                A1[mm] = fmaf(wmi, j1, A1[mm]);
                A2[mm] = fmaf(wmi, j2, A2[mm]);
                A3[mm] = fmaf(wmi, j3, A3[mm]);
                A4[mm] = fmaf(wmi, j4, A4[mm]);
                A5[mm] = fmaf(wmi, j5, A5[mm]);
                A6[mm] = fmaf(wmi, j6, A6[mm]);
                A7[mm] = fmaf(wmi, j7, A7[mm]);
                A8[mm] = fmaf(wmi, j8, A8[mm]);
            }
        }
        float Fyy = 0.f, Fyz = 0.f, Fzz = 0.f, Fyyz = 0.f, Fyzz = 0.f, Fzzz = 0.f;
#pragma unroll
        for (int mm = 0; mm < 8; ++mm) {
            int m = slice * 8 + mm;
            float G0 = A0[mm] + lds[SW_BE2 + m];
            float v = tanh_fast(G0);
            float s = 1.f - v * v;
            float f2 = -2.f * v * s;
            float f3 = 2.f * s * (2.f * v * v - s);
            float Gy = A1[mm], Gz = A2[mm];
            float Gyy = -2.f * A3[mm], Gyz = -2.f * A4[mm], Gzz = -2.f * A5[mm];
            float Gyyz = 2.f * A6[mm], Gyzz = 2.f * A7[mm], Gzzz = 2.f * A8[mm];
            float Hyy = f2 * Gy * Gy + s * Gyy;
            float Hyz = f2 * Gy * Gz + s * Gyz;
            float Hzz = f2 * Gz * Gz + s * Gzz;
            float Hyyz = f3 * Gy * Gy * Gz + f2 * (Gyy * Gz + 2.f * Gyz * Gy) + s * Gyyz;
            float Hyzz = f3 * Gy * Gz * Gz + f2 * (2.f * Gyz * Gz + Gzz * Gy) + s * Gyzz;
            float Hzzz = f3 * Gz * Gz * Gz + 3.f * f2 * Gzz * Gz + s * Gzzz;
            float w3 = lds[SW_WE3 + m];
            Fyy  = fmaf(w3, Hyy,  Fyy);
            Fyz  = fmaf(w3, Hyz,  Fyz);
            Fzz  = fmaf(w3, Hzz,  Fzz);
            Fyyz = fmaf(w3, Hyyz, Fyyz);
            Fyzz = fmaf(w3, Hyzz, Fyzz);
            Fzzz = fmaf(w3, Hzzz, Fzzz);
        }
        lds[FREDP + 0 * 512 + slice * 64 + p] = Fyy;   // plane-major
        lds[FREDP + 1 * 512 + slice * 64 + p] = Fyz;
        lds[FREDP + 2 * 512 + slice * 64 + p] = Fzz;
        lds[FREDP + 3 * 512 + slice * 64 + p] = Fyyz;
        lds[FREDP + 4 * 512 + slice * 64 + p] = Fyzz;
        lds[FREDP + 5 * 512 + slice * 64 + p] = Fzzz;
    }
    __syncthreads();

    // ---- reduce F partials + combine (threads 0..63) ----
    if (tid < 64) {
        float F[6] = {0.f, 0.f, 0.f, 0.f, 0.f, 0.f};
#pragma unroll
        for (int s = 0; s < 8; ++s) {
#pragma unroll
            for (int q = 0; q < 6; ++q) F[q] += lds[FREDP + q * 512 + s * 64 + tid];
        }
        float u1r = lds[UREDP + 1 * 64 + tid];
        float u2r = lds[UREDP + 2 * 64 + tid];
        float u3r = lds[UREDP + 3 * 64 + tid];
        float F_yx  = F[0] * u1r + F[1] * u2r;
        float F_zxx = F[1] * u2r + F[2] * u3r + F[3] * u1r * u1r
                    + 2.f * F[4] * u1r * u2r + F[5] * u2r * u2r;
        out[blockIdx.x * 64 + tid] = F_zxx - F_yx;
    }
}

extern "C" void kernel_launch(void* const* d_in, const int* in_sizes, int n_in,
                              void* d_out, int out_size, void* d_ws, size_t ws_size,
                              hipStream_t stream) {
    const float* a   = (const float*)d_in[0];
    const float* x   = (const float*)d_in[1];
    const float* t   = (const float*)d_in[2];
    const float* Wb  = (const float*)d_in[3];
    const float* bb  = (const float*)d_in[4];
    const float* Wt1 = (const float*)d_in[5];
    const float* bt1 = (const float*)d_in[6];
    const float* Wt2 = (const float*)d_in[7];
    const float* bt2 = (const float*)d_in[8];
    const float* Wt3 = (const float*)d_in[9];
    const float* bt3 = (const float*)d_in[10];
    const float* We1 = (const float*)d_in[11];
    const float* be1 = (const float*)d_in[12];
    const float* We2 = (const float*)d_in[13];
    const float* be2 = (const float*)d_in[14];
    const float* We3 = (const float*)d_in[15];

    float* ws = (float*)d_ws;
    float* out = (float*)d_out;

    // 2 launches: gemv (+transpose tail blocks y>=32) -> point (inlined prep).
    gemv_k<<<dim3(128, 34), 256, 0, stream>>>(Wb, a, Wt2, We2, Wt3, ws);
    point_k<<<NXP / 64, 512, 0, stream>>>(x, t, Wt1, bt1, bt2, We1, be1, be2, We3,
                                          bb, bt3, ws, out);
}